// Round 13
// baseline (67.098 us; speedup 1.0000x reference)
//
#include <hip/hip_runtime.h>
#include <hip/hip_bf16.h>
#include <hip/hip_fp8.h>

// AlignConLoss: loss = sum_j [ log(sum_i exp(cn_i . an_j)) - cn_j . an_j ]
// B = 8192, D = 256, fp32 inputs, scalar fp32 out. sim in [-1,1] -> no max.
//
// R12 -> R13: NO-LDS gemm. R8-R12 evidence: the wall was the
// global->LDS->reg->MFMA latency chain (2-deep, 8-16 waves/CU), not
// bandwidth, not MFMA rate, not barriers. With fp8 rows = 256 B, each
// lane's 32 B MFMA fragment loads directly global->VGPR (i32x8, aligned,
// wave fully consumes each row -> no overfetch). No LDS, no barriers, no
// inline-asm waitcnt: plain loads + MFMA, compiler-scheduled. af (C-rows)
// held in 64 VGPR; bf (A-cols) hand-pipelined 1-ahead with two named
// register sets (static indexing). MX-fp8 mfma_scale 16x16x128, scale=1.

#define BROWS 8192
#define DIM   256

typedef int   i32x8 __attribute__((ext_vector_type(8)));
typedef float f32x4 __attribute__((ext_vector_type(4)));

__device__ __forceinline__ unsigned char to_e4m3(float v) {
  __hip_fp8_e4m3 t(v);
  return *reinterpret_cast<unsigned char*>(&t);
}

// ---------------------------------------------------------------------------
// Kernel 1: per-row L2 norms -> fp8 e4m3 normalized An/Cn; exact fp32 diag.
// One wave per row. Blocks 0..31 also zero colsum[8192].
// ---------------------------------------------------------------------------
__global__ __launch_bounds__(256) void prep_kernel(
    const float* __restrict__ E1, const float* __restrict__ E2,
    unsigned char* __restrict__ An8, unsigned char* __restrict__ Cn8,
    float* __restrict__ diag, float* __restrict__ colsum) {
  if (blockIdx.x < 32) colsum[blockIdx.x * 256 + threadIdx.x] = 0.f;

  const int w    = threadIdx.x >> 6;
  const int lane = threadIdx.x & 63;
  const int row  = blockIdx.x * 4 + w;
  const size_t base = (size_t)row * DIM + lane * 4;

  const float4 a = *(const float4*)(E1 + base);
  const float4 c = *(const float4*)(E2 + base);

  float sa  = a.x*a.x + a.y*a.y + a.z*a.z + a.w*a.w;
  float sc  = c.x*c.x + c.y*c.y + c.z*c.z + c.w*c.w;
  float sac = a.x*c.x + a.y*c.y + a.z*c.z + a.w*c.w;
#pragma unroll
  for (int o = 32; o > 0; o >>= 1) {
    sa  += __shfl_down(sa,  o);
    sc  += __shfl_down(sc,  o);
    sac += __shfl_down(sac, o);
  }
  const float inva = 1.0f / fmaxf(sqrtf(__shfl(sa, 0)), 1e-8f);
  const float invc = 1.0f / fmaxf(sqrtf(__shfl(sc, 0)), 1e-8f);

  uchar4 pa, pc;
  pa.x = to_e4m3(a.x * inva); pa.y = to_e4m3(a.y * inva);
  pa.z = to_e4m3(a.z * inva); pa.w = to_e4m3(a.w * inva);
  pc.x = to_e4m3(c.x * invc); pc.y = to_e4m3(c.y * invc);
  pc.z = to_e4m3(c.z * invc); pc.w = to_e4m3(c.w * invc);
  *(uchar4*)(An8 + base) = pa;
  *(uchar4*)(Cn8 + base) = pc;
  if (lane == 0) diag[row] = sac * inva * invc;
}

// ---------------------------------------------------------------------------
// Kernel 2: NO-LDS MX-fp8 gemm+colsum. Block = 128 i x 256 j; grid =
// 64 itiles x 32 jgroups = 2048. Wave (ih = w&1, js = w>>1) owns
// 64 i-rows x 128 j-cols, loops 8 jtiles of 16 cols.
// Fragment load (per lane): row r -> bytes [q*32 + W*128, +32) of that row,
// one aligned i32x8. A-frag rows = Cn8[i0+ih*64+m*16+rb]; B-frag rows =
// An8[jw+jj*16+rb]. A wave's 8 loads fully consume each 256 B row.
// Epilogue per jtile: exp, shfl_xor(16,32) row-group combine, one 16-lane
// atomicAdd into colsum. C/D layout: col=lane&15, row=(lane>>4)*4+reg.
// ---------------------------------------------------------------------------
__global__ __launch_bounds__(256) void gemm_colsum_kernel(
    const unsigned char* __restrict__ Cn8,   // contrast rows -> sim rows i
    const unsigned char* __restrict__ An8,   // anchor rows   -> sim cols j
    float* __restrict__ colsum) {
  const int tid  = threadIdx.x;
  const int lane = tid & 63;
  const int w    = tid >> 6;      // 4 waves
  const int ih   = w & 1;         // i-half: 64 rows
  const int js   = w >> 1;        // j-strip: 128 cols

  const int jgroup = blockIdx.x & 31;
  const int itile  = blockIdx.x >> 5;
  const int i0 = itile * 128;
  const int jw = jgroup * 256 + js * 128;

  const int q  = lane >> 4;       // k-quarter within a K=128 window
  const int rb = lane & 15;
  const int SC = 0x7F7F7F7F;      // e8m0 127 -> scale 1.0

  // ---- A-side (C-rows) fragments: loaded once, held in 64 VGPR.
  const unsigned char* cb =
      Cn8 + (size_t)(i0 + ih * 64 + rb) * DIM + q * 32;
  i32x8 af[4][2];
#pragma unroll
  for (int m = 0; m < 4; ++m)
#pragma unroll
    for (int W = 0; W < 2; ++W)
      af[m][W] = *(const i32x8*)(cb + (size_t)m * 16 * DIM + W * 128);

  const unsigned char* ab = An8 + (size_t)(jw + rb) * DIM + q * 32;

  auto loadB = [&](i32x8* b, int jj) {
#pragma unroll
    for (int W = 0; W < 2; ++W)
      b[W] = *(const i32x8*)(ab + (size_t)jj * 16 * DIM + W * 128);
  };

  auto compute = [&](const i32x8* b, int jj) {
    f32x4 acc[4] = {};
    __builtin_amdgcn_s_setprio(1);
#pragma unroll
    for (int m = 0; m < 4; ++m)
#pragma unroll
      for (int W = 0; W < 2; ++W)
        acc[m] = __builtin_amdgcn_mfma_scale_f32_16x16x128_f8f6f4(
            af[m][W], b[W], acc[m], 0, 0, 0, SC, 0, SC);
    __builtin_amdgcn_s_setprio(0);

    float s = 0.f;
#pragma unroll
    for (int m = 0; m < 4; ++m) {
      const f32x4 v = acc[m];
      s += __expf(v[0]) + __expf(v[1]) + __expf(v[2]) + __expf(v[3]);
    }
    s += __shfl_xor(s, 16);
    s += __shfl_xor(s, 32);
    if (lane < 16) atomicAdd(&colsum[jw + jj * 16 + lane], s);
  };

  // ---- 8 jtiles, 1-ahead pipelined with two named register sets.
  i32x8 b0[2], b1[2];
  loadB(b0, 0);
#pragma unroll
  for (int jp = 0; jp < 4; ++jp) {
    const int ja = jp * 2, jb = jp * 2 + 1;
    loadB(b1, jb);                 // in flight during compute(ja)
    compute(b0, ja);
    if (jb + 1 <= 7) loadB(b0, jb + 1);
    compute(b1, jb);
  }
}

// ---------------------------------------------------------------------------
// Kernel 3: loss = sum_j log(colsum[j]) - diag[j].  Single block.
// ---------------------------------------------------------------------------
__global__ __launch_bounds__(256) void finalize_kernel(
    const float* __restrict__ colsum, const float* __restrict__ diag,
    float* __restrict__ out) {
  const int t = threadIdx.x;
  float s = 0.f;
  for (int j = t; j < BROWS; j += 256) s += logf(colsum[j]) - diag[j];
#pragma unroll
  for (int o = 32; o > 0; o >>= 1) s += __shfl_down(s, o);
  __shared__ float red[4];
  if ((t & 63) == 0) red[t >> 6] = s;
  __syncthreads();
  if (t == 0) out[0] = red[0] + red[1] + red[2] + red[3];
}

// ---------------------------------------------------------------------------
// ws layout (~4.07 MB):
//   [0, 2MiB)            Cn8 fp8 [8192*256]
//   [2MiB, 4MiB)         An8 fp8 [8192*256]
//   [4MiB, +32KiB)       colsum f32 [8192]
//   [4MiB+32K, +32KiB)   diag   f32 [8192]
// ---------------------------------------------------------------------------
extern "C" void kernel_launch(void* const* d_in, const int* in_sizes, int n_in,
                              void* d_out, int out_size, void* d_ws, size_t ws_size,
                              hipStream_t stream) {
  const float* E1 = (const float*)d_in[0];   // encoder_embedding1 -> anchors
  const float* E2 = (const float*)d_in[1];   // encoder_embedding2 -> contrast
  char* ws = (char*)d_ws;
  unsigned char* Cn8 = (unsigned char*)(ws);
  unsigned char* An8 = (unsigned char*)(ws + (size_t)2 * 1024 * 1024);
  float* colsum = (float*)(ws + (size_t)4 * 1024 * 1024);
  float* diag   = (float*)(ws + (size_t)4 * 1024 * 1024 + 32 * 1024);
  float* out = (float*)d_out;

  prep_kernel<<<BROWS / 4, 256, 0, stream>>>(E1, E2, An8, Cn8, diag, colsum);
  gemm_colsum_kernel<<<64 * 32, 256, 0, stream>>>(Cn8, An8, colsum);
  finalize_kernel<<<1, 256, 0, stream>>>(colsum, diag, out);
}